// Round 6
// baseline (717.430 us; speedup 1.0000x reference)
//
#include <hip/hip_runtime.h>
#include <hip/hip_bf16.h>
#include <math.h>

// B=12, C=64, V=32768, K=32, mid=32, red=16.
// Inputs fp32 (runtime-probed, bf16 fallback path kept). Outputs fp32.
// ws layout (float offsets):
#define REG_OFF    0
#define ORTHO_OFF  1
#define FLAG_OFF   2          // 1.0 = inputs fp32, 0.0 = bf16
#define MSUM_OFF   4          // [32]
#define RF_OFF     64         // [12][32][64] fp32
#define G_OFF      24640      // [12][64][64] fp32
#define WKW_OFF    73792      // [12][32] fp32
#define MODTB_OFF  74176      // u16 region: modT bf16 [12][64 o][32 k]   (24576 u16 = 12288 f)
#define M1TTH_OFF  86464      // u16: M1T^T hi bf16 [64 o][64 c]          (4096 u16 = 2048 f)
#define M1TTL_OFF  88512      // u16: M1T^T lo bf16 [64 o][64 c]          (4096 u16 = 2048 f)
#define WKCB_OFF   90560      // u16: folded conv W bf16 [12][64 o][27 d][32 k] (663552 u16)
#define IPK_OFF    422336     // fp32 [32][144] region Gram of rf (x2 = diagonal)
#define WS_TOTAL   426944
#define ZERO_FLOATS 73792     // zero: scalars + flag + MSUM + RF + G

#define RF_OUT   0
#define SPAT_OUT 24576
#define ZOUT_OUT 417792
#define SCAL_OUT 25583616

typedef unsigned short u16;
typedef short bh8 __attribute__((ext_vector_type(8)));   // 8 bf16 (bit patterns)
typedef float fv4 __attribute__((ext_vector_type(4)));   // MFMA accumulator

__device__ __forceinline__ float bf2f(u16 u) {
  union { unsigned int i; float f; } x; x.i = ((unsigned int)u) << 16; return x.f;
}
__device__ __forceinline__ u16 f2bf(float f) {   // round-to-nearest-even
  unsigned int u = __float_as_uint(f);
  return (u16)((u + 0x7fffu + ((u >> 16) & 1u)) >> 16);
}
__device__ __forceinline__ float ldin(const void* p, size_t i, bool f32) {
  return f32 ? ((const float*)p)[i] : bf2f(((const u16*)p)[i]);
}
// 8 mask bits (low byte of mbits) -> 8 bf16 values 0.0/1.0
__device__ __forceinline__ bh8 bits2bf8(unsigned int mbits) {
  union { bh8 v; unsigned int w[4]; } u;
#pragma unroll
  for (int j = 0; j < 4; j++) {
    unsigned int tt = mbits >> (2 * j);
    u.w[j] = ((tt & 1u) | ((tt & 2u) << 15)) * 0x3F80u;
  }
  return u.v;
}

// ---------------- input dtype probe ----------------
__global__ void k_probe(const void* __restrict__ Z, float* __restrict__ ws) {
  int t = threadIdx.x;
  const u16* s = (const u16*)Z;
  float mx = 0.f;
  for (int i = t; i < 8192; i += 256) {
    float a = fabsf(bf2f(s[i]));
    if (!(a < 1e30f)) a = 3e38f;   // NaN/Inf count as huge
    mx = fmaxf(mx, a);
  }
  __shared__ float r[256];
  r[t] = mx; __syncthreads();
  for (int o = 128; o > 0; o >>= 1) { if (t < o) r[t] = fmaxf(r[t], r[t + o]); __syncthreads(); }
  if (t == 0) ws[FLAG_OFF] = (r[0] > 1e6f) ? 1.f : 0.f;
}

// ---------------- masks region sizes ----------------
__global__ void k_msum(const void* __restrict__ masks, float* __restrict__ ws) {
  int k = blockIdx.x, t = threadIdx.x;
  bool f32 = ws[FLAG_OFF] > 0.5f;
  float s = 0.f;
  for (int v = t; v < 32768; v += 256) s += ldin(masks, ((size_t)k << 15) + v, f32);
  __shared__ float red[256];
  red[t] = s; __syncthreads();
  for (int off = 128; off > 0; off >>= 1) { if (t < off) red[t] += red[t + off]; __syncthreads(); }
  if (t == 0) ws[MSUM_OFF + k] = red[0];
}

// ---------------- rf partials + channel Gram ----------------
__global__ __launch_bounds__(256) void k_rfgram(const void* __restrict__ Z,
                                                const void* __restrict__ masks,
                                                float* __restrict__ ws) {
  __shared__ float Zt[64][68];
  __shared__ float Mt[64][36];
  int b = blockIdx.y, t = threadIdx.x;
  bool f32 = ws[FLAG_OFF] > 0.5f;
  int ci = t & 15, gj = t >> 4;
  int c0 = ci << 2, c20 = gj << 2, k0 = gj << 1;
  float accG[16], accR[8];
#pragma unroll
  for (int i = 0; i < 16; i++) accG[i] = 0.f;
#pragma unroll
  for (int i = 0; i < 8; i++) accR[i] = 0.f;
  int vs = blockIdx.x << 9;
  for (int t8 = 0; t8 < 8; t8++) {
    int vb = vs + (t8 << 6);
    __syncthreads();
    if (f32) {
      const float* Zf = (const float*)Z;
      const float* Mf = (const float*)masks;
#pragma unroll
      for (int i = 0; i < 8; i++) {
        int idx = (i << 8) + t, c = idx >> 5, v2 = (idx & 31) << 1;
        float2 u = *(const float2*)(Zf + (((size_t)(b << 6) + c) << 15) + vb + v2);
        Zt[v2][c] = u.x; Zt[v2 + 1][c] = u.y;
      }
#pragma unroll
      for (int i = 0; i < 4; i++) {
        int idx = (i << 8) + t, k = idx >> 5, v2 = (idx & 31) << 1;
        float2 u = *(const float2*)(Mf + ((size_t)k << 15) + vb + v2);
        Mt[v2][k] = u.x; Mt[v2 + 1][k] = u.y;
      }
    } else {
      const u16* Zs = (const u16*)Z;
      const u16* Ms = (const u16*)masks;
#pragma unroll
      for (int i = 0; i < 8; i++) {
        int idx = (i << 8) + t, c = idx >> 5, v2 = (idx & 31) << 1;
        unsigned int u = *(const unsigned int*)(Zs + (((size_t)(b << 6) + c) << 15) + vb + v2);
        Zt[v2][c]     = bf2f((u16)(u & 0xffff));
        Zt[v2 + 1][c] = bf2f((u16)(u >> 16));
      }
#pragma unroll
      for (int i = 0; i < 4; i++) {
        int idx = (i << 8) + t, k = idx >> 5, v2 = (idx & 31) << 1;
        unsigned int u = *(const unsigned int*)(Ms + ((size_t)k << 15) + vb + v2);
        Mt[v2][k]     = bf2f((u16)(u & 0xffff));
        Mt[v2 + 1][k] = bf2f((u16)(u >> 16));
      }
    }
    __syncthreads();
    for (int vt = 0; vt < 64; vt++) {
      float4 z1 = *(const float4*)&Zt[vt][c0];
      float4 z2 = *(const float4*)&Zt[vt][c20];
      float2 m2 = *(const float2*)&Mt[vt][k0];
      float z1a[4] = {z1.x, z1.y, z1.z, z1.w};
      float z2a[4] = {z2.x, z2.y, z2.z, z2.w};
      float m2a[2] = {m2.x, m2.y};
#pragma unroll
      for (int i = 0; i < 4; i++) {
#pragma unroll
        for (int j = 0; j < 4; j++) accG[(i << 2) + j] += z1a[i] * z2a[j];
#pragma unroll
        for (int kk = 0; kk < 2; kk++) accR[(i << 1) + kk] += z1a[i] * m2a[kk];
      }
    }
  }
  float* Gd = ws + G_OFF + (b << 12);
  float* Rd = ws + RF_OFF + (b << 11);
#pragma unroll
  for (int i = 0; i < 4; i++) {
#pragma unroll
    for (int j = 0; j < 4; j++) atomicAdd(Gd + ((c0 + i) << 6) + c20 + j, accG[(i << 2) + j]);
#pragma unroll
    for (int kk = 0; kk < 2; kk++) atomicAdd(Rd + ((k0 + kk) << 6) + c0 + i, accR[(i << 1) + kk]);
  }
}

// ---------------- scale rf, emit fp32 rf ----------------
__global__ void k_scale_rf(float* __restrict__ ws, float* __restrict__ out) {
  int i = blockIdx.x * 256 + threadIdx.x;  // < 24576
  int k = (i >> 6) & 31;
  float v = ws[RF_OFF + i] / (ws[MSUM_OFF + k] + 1e-6f);
  ws[RF_OFF + i] = v;
  out[RF_OUT + i] = v;
}

// ---------------- region Gram: ipk[k][i][j] = <rf[i,k,:], rf[j,k,:]> ----------------
__global__ void k_ipk(float* __restrict__ ws) {
  __shared__ float rfk[12][65];   // +1 pad: avoid same-bank i-stride
  int k = blockIdx.x, t = threadIdx.x;
  for (int i = t; i < 768; i += 256) {
    int b = i >> 6, c = i & 63;
    rfk[b][c] = ws[RF_OFF + (((size_t)(b << 5) + k) << 6) + c];
  }
  __syncthreads();
  if (t < 144) {
    int i = t / 12, j = t - (t / 12) * 12;
    float s = 0.f;
#pragma unroll
    for (int c = 0; c < 64; c++) s += rfk[i][c] * rfk[j][c];
    ws[IPK_OFF + k * 144 + t] = s;
  }
}

// ---------------- MMD (128-way parallel) + reg + Wk weights ----------------
__global__ void k_mmdw(const int* __restrict__ labels, const void* __restrict__ ages,
                       const void* __restrict__ prior, float* __restrict__ ws) {
  __shared__ float IPL[32 * 145];   // stride 145: bank-spread across k
  __shared__ float dpart[128];
  __shared__ float Dm[32], nms[32], bases[32], pwl[32];
  __shared__ int labs[12];
  int t = threadIdx.x;
  bool f32 = ws[FLAG_OFF] > 0.5f;
  if (t < 12) labs[t] = labels[t];
  for (int i = t; i < 4608; i += 256) {
    int k = i / 144, r = i - k * 144;
    IPL[k * 145 + r] = ws[IPK_OFF + i];
  }
  __syncthreads();
  if (t < 128) {
    int k = t >> 2, s = t & 3;
    const float inv2s2[4] = {50.f, 2.f, 0.5f, 0.125f};   // 1/(2*sigma^2)
    float inv = inv2s2[s];
    const float* pk = IPL + k * 145;
    // class counts (labels wave-uniform)
    float c0 = 0.f, c1 = 0.f, c2 = 0.f;
#pragma unroll
    for (int i = 0; i < 12; i++) {
      int li = labs[i];
      c0 += (li == 0) ? 1.f : 0.f;
      c1 += (li == 1) ? 1.f : 0.f;
      c2 += (li == 2) ? 1.f : 0.f;
    }
    float s00=0,s01=0,s02=0,s10=0,s11=0,s12=0,s20=0,s21=0,s22=0;
    float dg0=0, dg1=0, dg2=0;
    for (int i = 0; i < 12; i++) {
      int li = labs[i];                    // wave-uniform
      float x2i = pk[i * 13];              // diagonal = |rf_i|^2
      float r0=0, r1=0, r2=0, dge=0;
      for (int j = 0; j < 12; j++) {
        float d2 = fmaxf(x2i + pk[j * 13] - 2.f * pk[i * 12 + j], 0.f);
        float e = expf(-d2 * inv);
        int lj = labs[j];                  // wave-uniform
        r0 += (lj == 0) ? e : 0.f;
        r1 += (lj == 1) ? e : 0.f;
        r2 += (lj == 2) ? e : 0.f;
        if (j == i) dge = e;
      }
      if (li == 0)      { s00 += r0; s01 += r1; s02 += r2; dg0 += dge; }
      else if (li == 1) { s10 += r0; s11 += r1; s12 += r2; dg1 += dge; }
      else              { s20 += r0; s21 += r1; s22 += r2; dg2 += dge; }
    }
    float ta = (s22 - dg2) / (c2 * (c2 - 1.f));
    float tb = (s00 - dg0) / (c0 * (c0 - 1.f));
    float tc = (s11 - dg1) / (c1 * (c1 - 1.f));
    float dsum = (ta + tb - 2.f * s20 / (c2 * c0))     // (AD,CN)
               + (tc + tb - 2.f * s10 / (c1 * c0))     // (MCI,CN)
               + (ta + tc - 2.f * s21 / (c2 * c1));    // (AD,MCI)
    dpart[t] = dsum;
  }
  __syncthreads();
  if (t < 32) {
    Dm[t] = (dpart[t * 4] + dpart[t * 4 + 1] + dpart[t * 4 + 2] + dpart[t * 4 + 3]) * 0.25f;
    pwl[t] = (float)ldin(prior, t, f32);
  }
  __syncthreads();
  if (t == 0) {
    float mx = 1e-6f;
    for (int k = 0; k < 32; k++) mx = fmaxf(mx, Dm[k]);
    float nmax = -1e30f, pmax = -1e30f;
    for (int k = 0; k < 32; k++) {
      nms[k] = fmaxf(Dm[k] / mx, 0.f);
      nmax = fmaxf(nmax, nms[k]);
      pmax = fmaxf(pmax, pwl[k]);
    }
    float nse = 0.f, pse = 0.f;
    for (int k = 0; k < 32; k++) { nse += expf(nms[k] - nmax); pse += expf(pwl[k] - pmax); }
    float lns = logf(nse), lps = logf(pse);
    float reg = 0.f;
    for (int k = 0; k < 32; k++) {
      float lqk = nms[k] - nmax - lns;
      float lpk = pwl[k] - pmax - lps;
      reg += 0.5f * (expf(lqk) * (lqk - lpk) + expf(lpk) * (lpk - lqk));
    }
    ws[REG_OFF] = reg / 32.f;
    for (int k = 0; k < 32; k++) bases[k] = 0.7f * pwl[k] + 0.3f * nms[k];
  }
  __syncthreads();
  if (t < 12) {
    float x = 0.1f * (ldin(ages, t, f32) - 50.f);
    float af = 1.f + fmaxf(x, 0.f) + log1pf(expf(-fabsf(x)));
    float w[32];
    float mx = -1e30f;
#pragma unroll
    for (int k = 0; k < 32; k++) {
      float v = fminf(fmaxf(bases[k] * af, 0.f), 2.f);
      w[k] = v; mx = fmaxf(mx, v);
    }
    float se = 0.f;
#pragma unroll
    for (int k = 0; k < 32; k++) se += expf(w[k] - mx);
#pragma unroll
    for (int k = 0; k < 32; k++) ws[WKW_OFF + (t << 5) + k] = expf(w[k] - mx) / se;
  }
}

// ---------------- channel modulation MLP per (b,k) -> modT bf16 ----------------
__global__ __launch_bounds__(64) void k_mod(const void* __restrict__ m_w1, const void* __restrict__ m_b1,
                                            const void* __restrict__ m_w2, const void* __restrict__ m_b2,
                                            float* __restrict__ ws) {
  __shared__ float W1[16][65];   // padded
  __shared__ float W2T[16][64];  // transposed: [rr][c]
  __shared__ float B1[16], B2[64], RL[64], H[16];
  int bk = blockIdx.x, t = threadIdx.x;
  int bb = bk >> 5, kk = bk & 31;
  bool f32 = ws[FLAG_OFF] > 0.5f;
  for (int i = t; i < 1024; i += 64) {
    W1[i >> 6][i & 63] = ldin(m_w1, i, f32);      // m_w1[rr][c]
    W2T[i & 15][i >> 4] = ldin(m_w2, i, f32);     // m_w2[c][rr] -> [rr][c]
  }
  if (t < 16) B1[t] = ldin(m_b1, t, f32);
  B2[t] = ldin(m_b2, t, f32);
  RL[t] = ws[RF_OFF + (bk << 6) + t];
  __syncthreads();
  if (t < 16) {
    float s = B1[t];
#pragma unroll
    for (int c = 0; c < 64; c++) s += RL[c] * W1[t][c];
    H[t] = fmaxf(s, 0.f);
  }
  __syncthreads();
  {
    int c = t;
    float s = B2[c];
#pragma unroll
    for (int rr = 0; rr < 16; rr++) s += H[rr] * W2T[rr][c];
    float mv = fmaxf(s, 0.f) + log1pf(expf(-fabsf(s)));
    ((u16*)(ws + MODTB_OFF))[((size_t)bb * 64 + c) * 32 + kk] = f2bf(mv);
  }
}

// ---------------- M1T^T = (up_w @ struct_w)^T, bf16 hi/lo ----------------
__global__ void k_m1t(const void* __restrict__ struct_w, const void* __restrict__ up_w,
                      float* __restrict__ ws) {
  __shared__ float UPT[32][64];  // transposed: [j][co]
  __shared__ float ST[32][64];   // [j][cin]
  int t = threadIdx.x, blk = blockIdx.x;
  bool f32 = ws[FLAG_OFF] > 0.5f;
  for (int i = t; i < 2048; i += 256) {
    UPT[i & 31][i >> 5] = ldin(up_w, i, f32);     // up_w[co][j] -> [j][co]
    ST[i >> 6][i & 63] = ldin(struct_w, i, f32);  // struct_w[j][cin]
  }
  __syncthreads();
  int idx = (blk << 8) + t;   // 0..4095
  int cin = idx >> 6, co = idx & 63;
  float s = 0.f;
#pragma unroll
  for (int j = 0; j < 32; j++) s += UPT[j][co] * ST[j][cin];
  u16 hi = f2bf(s);
  ((u16*)(ws + M1TTH_OFF))[co * 64 + cin] = hi;
  ((u16*)(ws + M1TTL_OFF))[co * 64 + cin] = f2bf(s - bf2f(hi));
}

// ---------------- ortho from Gram ----------------
__global__ void k_ortho(const void* __restrict__ sw, const void* __restrict__ nw,
                        float* __restrict__ ws) {
  int b = blockIdx.x >> 5, o = blockIdx.x & 31, c = threadIdx.x;
  bool f32 = ws[FLAG_OFF] > 0.5f;
  const float* Gb = ws + G_OFF + (b << 12);
  float ts = 0.f, tn = 0.f;
  for (int c2 = 0; c2 < 64; c2++) {
    float g = Gb[(c << 6) + c2];
    ts += g * ldin(sw, (o << 6) + c2, f32);
    tn += g * ldin(nw, (o << 6) + c2, f32);
  }
  float swc = ldin(sw, (o << 6) + c, f32);
  float nwc = ldin(nw, (o << 6) + c, f32);
  float ds = swc * tn, ss = swc * ts, nn = nwc * tn;
  for (int off = 32; off > 0; off >>= 1) {
    ds += __shfl_down(ds, off);
    ss += __shfl_down(ss, off);
    nn += __shfl_down(nn, off);
  }
  if (c == 0) {
    ss = fmaxf(ss, 0.f); nn = fmaxf(nn, 0.f);
    float cosv = ds / (fmaxf(sqrtf(ss), 1e-8f) * fmaxf(sqrtf(nn), 1e-8f));
    atomicAdd(ws + ORTHO_OFF, fabsf(cosv) * (1.f / 384.f));
  }
}

// ---------------- folded conv weights -> bf16 [b][o][d][k] ----------------
__global__ void k_wk(const void* __restrict__ rw, float* __restrict__ ws) {
  int bk = blockIdx.x;  // b*32+k
  int b = bk >> 5, k = bk & 31;
  int t = threadIdx.x;
  bool f32 = ws[FLAG_OFF] > 0.5f;
  __shared__ float rl[64];
  if (t < 64) rl[t] = ws[RF_OFF + (bk << 6) + t];
  __syncthreads();
  u16* dst = (u16*)(ws + WKCB_OFF);
  for (int idx = t; idx < 1728; idx += 256) {
    int o = idx / 27, d = idx - o * 27;
    float s = 0.f;
    for (int c = 0; c < 64; c++) s += rl[c] * ldin(rw, (size_t)o * 1728 + c * 27 + d, f32);
    dst[(((size_t)b * 64 + o) * 27 + d) * 32 + k] = f2bf(s);   // kd = d*32+k
  }
}

// ---------------- spatial output (fp32) ----------------
__global__ void k_spatial(const void* __restrict__ masks, const float* __restrict__ ws,
                          float* __restrict__ out) {
  int b = blockIdx.y, t = threadIdx.x;
  bool f32 = ws[FLAG_OFF] > 0.5f;
  __shared__ float wl[32];
  if (t < 32) wl[t] = ws[WKW_OFF + (b << 5) + t];
  __syncthreads();
  int v0 = (blockIdx.x << 11) + (t << 3);
  float s[8] = {0, 0, 0, 0, 0, 0, 0, 0};
  for (int k = 0; k < 32; k++) {
    float wkv = wl[k];
    float mv[8];
    if (f32) {
      const float* Mf = (const float*)masks + ((size_t)k << 15) + v0;
      float4 a = *(const float4*)Mf, bb = *(const float4*)(Mf + 4);
      mv[0]=a.x; mv[1]=a.y; mv[2]=a.z; mv[3]=a.w; mv[4]=bb.x; mv[5]=bb.y; mv[6]=bb.z; mv[7]=bb.w;
    } else {
      uint4 u = *(const uint4*)((const u16*)masks + ((size_t)k << 15) + v0);
      mv[0]=bf2f((u16)(u.x & 0xffff)); mv[1]=bf2f((u16)(u.x >> 16));
      mv[2]=bf2f((u16)(u.y & 0xffff)); mv[3]=bf2f((u16)(u.y >> 16));
      mv[4]=bf2f((u16)(u.z & 0xffff)); mv[5]=bf2f((u16)(u.z >> 16));
      mv[6]=bf2f((u16)(u.w & 0xffff)); mv[7]=bf2f((u16)(u.w >> 16));
    }
#pragma unroll
    for (int j = 0; j < 8; j++) s[j] += wkv * mv[j];
  }
#pragma unroll
  for (int j = 0; j < 8; j++) out[SPAT_OUT + (b << 15) + v0 + j] = s[j];
}

// ---------------- fused final: MFMA GEMM, bitmask halo ----------------
// Masks are 0/1 -> halo stored as a 600-entry u32 BITMASK in LDS (bit k =
// region k). B-fragments are built in-register from bits (5 VALU per u32,
// word = ((t&1)|((t&2)<<15))*0x3F80), killing the v5 bank conflicts (16
// consecutive u32 reads/wave, lanes 16-63 broadcast) and shrinking LDS
// 48 KB -> ~4 KB. Z_clean B-fragments load straight from global (lane-
// consecutive -> 64B coalesced, L2-resident) -> no staging, no syncs.
__global__ __launch_bounds__(256, 4) void k_final(const void* __restrict__ Z,
                                                  const void* __restrict__ masks,
                                                  const float* __restrict__ ws,
                                                  float* __restrict__ out) {
  __shared__ unsigned int MHB[608];   // bitmask halo 6x10x10 (600 used)
  __shared__ float wl[32];
  __shared__ float spl[256];

  int b = blockIdx.y, tile = blockIdx.x, t = threadIdx.x;
  int lane = t & 63, w = t >> 6;
  int lo16 = lane & 15, g = lane >> 4, g8 = g << 3;
  bool f32 = ws[FLAG_OFF] > 0.5f;
  int d0 = (tile >> 4) << 2, h0 = ((tile >> 2) & 3) << 3, w0 = (tile & 3) << 3;

  // ---- phase 0: halo bitmask ----
  for (int r = t; r < 600; r += 256) {
    int hd = r / 100, rr = r - hd * 100, hh = rr / 10, hw = rr - hh * 10;
    int gd = d0 - 1 + hd, gh = h0 - 1 + hh, gw = w0 - 1 + hw;
    unsigned int word = 0;
    if ((unsigned)gd < 32u && (unsigned)gh < 32u && (unsigned)gw < 32u) {
      size_t base = (size_t)(gd << 10) + (gh << 5) + gw;
#pragma unroll 4
      for (int k = 0; k < 32; k++) {
        float mv = ldin(masks, ((size_t)k << 15) + base, f32);
        word |= (mv != 0.f ? 1u : 0u) << k;
      }
    }
    MHB[r] = word;
  }
  if (t < 32) wl[t] = ws[WKW_OFF + (b << 5) + t];
  __syncthreads();

  // per-thread pos: spl[pos = t]
  {
    int dz = t >> 6, hy = (t >> 3) & 7, wx = t & 7;
    unsigned int m = MHB[dz * 100 + hy * 10 + wx + 111];
    float sp = 0.f;
#pragma unroll
    for (int k = 0; k < 32; k++) sp += ((m >> k) & 1u) ? wl[k] : 0.f;
    spl[t] = sp;
  }

  // per-lane tile columns: pos = w*64 + pt*16 + lo16
  int hb4[4], v4[4];
#pragma unroll
  for (int pt = 0; pt < 4; pt++) {
    int pos = (w << 6) + (pt << 4) + lo16;
    int dz = pos >> 6, hy = (pos >> 3) & 7, wx = pos & 7;
    hb4[pt] = dz * 100 + hy * 10 + wx;
    v4[pt] = ((d0 + dz) << 10) + ((h0 + hy) << 5) + (w0 + wx);
  }

  fv4 acc[4][4];
#pragma unroll
  for (int ot = 0; ot < 4; ot++)
#pragma unroll
    for (int pt = 0; pt < 4; pt++) { acc[ot][pt][0]=0.f; acc[ot][pt][1]=0.f; acc[ot][pt][2]=0.f; acc[ot][pt][3]=0.f; }

  // ---- phase 1: conv GEMM, 27 K-steps (one spatial offset each) ----
  const u16* Wb = (const u16*)(ws + WKCB_OFF) + (size_t)b * 55296;
#pragma unroll 3
  for (int d = 0; d < 27; d++) {
    int da = d / 9, r9 = d - da * 9, db = r9 / 3, dc = r9 - db * 3;
    int off = da * 100 + db * 10 + dc;              // wave-uniform
    bh8 a[4];
#pragma unroll
    for (int ot = 0; ot < 4; ot++)
      a[ot] = *(const bh8*)(Wb + ((ot << 4) + lo16) * 864 + (d << 5) + g8);
#pragma unroll
    for (int pt = 0; pt < 4; pt++) {
      bh8 bv = bits2bf8(MHB[hb4[pt] + off] >> g8);
#pragma unroll
      for (int ot = 0; ot < 4; ot++)
        acc[ot][pt] = __builtin_amdgcn_mfma_f32_16x16x32_bf16(a[ot], bv, acc[ot][pt], 0, 0, 0);
    }
  }

  // ---- phase 2: mod GEMM (K=32) + fold ----
  {
    const u16* modtb = (const u16*)(ws + MODTB_OFF);
    bh8 am[4];
#pragma unroll
    for (int ot = 0; ot < 4; ot++)
      am[ot] = *(const bh8*)(modtb + ((size_t)b * 64 + (ot << 4) + lo16) * 32 + g8);
    fv4 zero4; zero4[0]=0.f; zero4[1]=0.f; zero4[2]=0.f; zero4[3]=0.f;
#pragma unroll
    for (int pt = 0; pt < 4; pt++) {
      bh8 bc = bits2bf8(MHB[hb4[pt] + 111] >> g8);
      float spf = 0.1f * spl[(w << 6) + (pt << 4) + lo16];
#pragma unroll
      for (int ot = 0; ot < 4; ot++) {
        fv4 mm = __builtin_amdgcn_mfma_f32_16x16x32_bf16(am[ot], bc, zero4, 0, 0, 0);
        acc[ot][pt] = acc[ot][pt] * mm * spf;
      }
    }
  }

  // ---- phase 3: Z_clean GEMM, B-fragments direct from global ----
  {
    const u16* m1tth = (const u16*)(ws + M1TTH_OFF);
    const u16* m1ttl = (const u16*)(ws + M1TTL_OFF);
#pragma unroll 1
    for (int st = 0; st < 2; st++) {
      int cb = st << 5;
#pragma unroll
      for (int pt = 0; pt < 4; pt++) {
        bh8 bh, bl;
#pragma unroll
        for (int j = 0; j < 8; j++) {
          float zv = ldin(Z, (((size_t)(b << 6) + cb + g8 + j) << 15) + v4[pt], f32);
          u16 h = f2bf(zv);
          bh[j] = (short)h;
          bl[j] = (short)f2bf(zv - bf2f(h));
        }
#pragma unroll
        for (int ot = 0; ot < 4; ot++) {
          bh8 ah = *(const bh8*)(m1tth + ((ot << 4) + lo16) * 64 + cb + g8);
          bh8 al = *(const bh8*)(m1ttl + ((ot << 4) + lo16) * 64 + cb + g8);
          acc[ot][pt] = __builtin_amdgcn_mfma_f32_16x16x32_bf16(ah, bh, acc[ot][pt], 0, 0, 0);
          acc[ot][pt] = __builtin_amdgcn_mfma_f32_16x16x32_bf16(ah, bl, acc[ot][pt], 0, 0, 0);
          acc[ot][pt] = __builtin_amdgcn_mfma_f32_16x16x32_bf16(al, bh, acc[ot][pt], 0, 0, 0);
        }
      }
    }
  }

  // ---- phase 4: store (D layout: row o = ot*16+g*4+r, col pos = pt*16+lo16) ----
#pragma unroll
  for (int ot = 0; ot < 4; ot++)
#pragma unroll
    for (int pt = 0; pt < 4; pt++)
#pragma unroll
      for (int r = 0; r < 4; r++) {
        int o = (ot << 4) + (g << 2) + r;
        out[(size_t)ZOUT_OUT + (((size_t)(b << 6) + o) << 15) + v4[pt]] = acc[ot][pt][r];
      }
  if ((t | tile | b) == 0) out[SCAL_OUT] = ws[REG_OFF] + ws[ORTHO_OFF];
}

extern "C" void kernel_launch(void* const* d_in, const int* in_sizes, int n_in,
                              void* d_out, int out_size, void* d_ws, size_t ws_size,
                              hipStream_t stream) {
  (void)in_sizes; (void)n_in; (void)out_size; (void)ws_size;
  const void* Z        = d_in[0];
  const void* masks    = d_in[1];
  const int*  labels   = (const int*)d_in[2];
  const void* ages     = d_in[3];
  const void* prior    = d_in[4];
  const void* struct_w = d_in[5];
  const void* noise_w  = d_in[6];
  const void* up_w     = d_in[7];
  const void* region_w = d_in[8];
  const void* m_w1     = d_in[9];
  const void* m_b1     = d_in[10];
  const void* m_w2     = d_in[11];
  const void* m_b2     = d_in[12];
  float* ws = (float*)d_ws;
  float* out = (float*)d_out;

  hipMemsetAsync(d_ws, 0, (size_t)ZERO_FLOATS * 4, stream);
  k_probe<<<1, 256, 0, stream>>>(Z, ws);
  k_msum<<<32, 256, 0, stream>>>(masks, ws);
  k_rfgram<<<dim3(64, 12), 256, 0, stream>>>(Z, masks, ws);
  k_scale_rf<<<96, 256, 0, stream>>>(ws, out);
  k_m1t<<<16, 256, 0, stream>>>(struct_w, up_w, ws);
  k_ipk<<<32, 256, 0, stream>>>(ws);
  k_mmdw<<<1, 256, 0, stream>>>(labels, ages, prior, ws);
  k_mod<<<384, 64, 0, stream>>>(m_w1, m_b1, m_w2, m_b2, ws);
  k_ortho<<<384, 64, 0, stream>>>(struct_w, noise_w, ws);
  k_wk<<<384, 256, 0, stream>>>(region_w, ws);
  k_spatial<<<dim3(16, 12), 256, 0, stream>>>(masks, ws, out);
  k_final<<<dim3(128, 12), 256, 0, stream>>>(Z, masks, ws, out);
}

// Round 7
// 619.739 us; speedup vs baseline: 1.1576x; 1.1576x over previous
//
#include <hip/hip_runtime.h>
#include <hip/hip_bf16.h>
#include <math.h>

// B=12, C=64, V=32768, K=32, mid=32, red=16.
// Inputs fp32 (runtime-probed, bf16 fallback path kept). Outputs fp32.
// ws layout (float offsets):
#define REG_OFF    0
#define ORTHO_OFF  1
#define FLAG_OFF   2          // 1.0 = inputs fp32, 0.0 = bf16
#define MSUM_OFF   4          // [32]
#define RF_OFF     64         // [12][32][64] fp32
#define G_OFF      24640      // [12][64][64] fp32
#define WKW_OFF    73792      // [12][32] fp32
#define MODTB_OFF  74176      // u16 region: modT bf16 [12][64 o][32 k]   (24576 u16 = 12288 f)
#define M1TTH_OFF  86464      // u16: M1T^T hi bf16 [64 o][64 c]          (4096 u16 = 2048 f)
#define M1TTL_OFF  88512      // u16: M1T^T lo bf16 [64 o][64 c]          (4096 u16 = 2048 f)
#define WKCB_OFF   90560      // u16: folded conv W bf16 [12][64 o][27 d][32 k] (663552 u16)
#define IPK_OFF    422336     // fp32 [32][144] region Gram of rf (x2 = diagonal)
#define MB_OFF     426944     // u32 [32768]: bit k = mask[k][v] != 0
#define WS_TOTAL   459712
#define ZERO_FLOATS 73792     // zero: scalars + flag + MSUM + RF + G

#define RF_OUT   0
#define SPAT_OUT 24576
#define ZOUT_OUT 417792
#define SCAL_OUT 25583616

typedef unsigned short u16;
typedef short bh8 __attribute__((ext_vector_type(8)));   // 8 bf16 (bit patterns)
typedef float fv4 __attribute__((ext_vector_type(4)));   // MFMA accumulator

__device__ __forceinline__ float bf2f(u16 u) {
  union { unsigned int i; float f; } x; x.i = ((unsigned int)u) << 16; return x.f;
}
__device__ __forceinline__ u16 f2bf(float f) {   // round-to-nearest-even
  unsigned int u = __float_as_uint(f);
  return (u16)((u + 0x7fffu + ((u >> 16) & 1u)) >> 16);
}
__device__ __forceinline__ float ldin(const void* p, size_t i, bool f32) {
  return f32 ? ((const float*)p)[i] : bf2f(((const u16*)p)[i]);
}
// 8 mask bits (low byte of mbits) -> 8 bf16 values 0.0/1.0
__device__ __forceinline__ bh8 bits2bf8(unsigned int mbits) {
  union { bh8 v; unsigned int w[4]; } u;
#pragma unroll
  for (int j = 0; j < 4; j++) {
    unsigned int tt = mbits >> (2 * j);
    u.w[j] = ((tt & 1u) | ((tt & 2u) << 15)) * 0x3F80u;
  }
  return u.v;
}

// ---------------- input dtype probe ----------------
__global__ void k_probe(const void* __restrict__ Z, float* __restrict__ ws) {
  int t = threadIdx.x;
  const u16* s = (const u16*)Z;
  float mx = 0.f;
  for (int i = t; i < 8192; i += 256) {
    float a = fabsf(bf2f(s[i]));
    if (!(a < 1e30f)) a = 3e38f;   // NaN/Inf count as huge
    mx = fmaxf(mx, a);
  }
  __shared__ float r[256];
  r[t] = mx; __syncthreads();
  for (int o = 128; o > 0; o >>= 1) { if (t < o) r[t] = fmaxf(r[t], r[t + o]); __syncthreads(); }
  if (t == 0) ws[FLAG_OFF] = (r[0] > 1e6f) ? 1.f : 0.f;
}

// ---------------- global mask bitmask: MB[v] bit k = mask[k][v]!=0 ----------------
__global__ void k_mb(const void* __restrict__ masks, float* __restrict__ ws) {
  int v = blockIdx.x * 256 + threadIdx.x;
  bool f32 = ws[FLAG_OFF] > 0.5f;
  unsigned int word = 0;
#pragma unroll 8
  for (int k = 0; k < 32; k++) {
    float mv = ldin(masks, ((size_t)k << 15) + v, f32);   // coalesced per k
    word |= (mv != 0.f ? 1u : 0u) << k;
  }
  ((unsigned int*)(ws + MB_OFF))[v] = word;
}

// ---------------- masks region sizes ----------------
__global__ void k_msum(const void* __restrict__ masks, float* __restrict__ ws) {
  int k = blockIdx.x, t = threadIdx.x;
  bool f32 = ws[FLAG_OFF] > 0.5f;
  float s = 0.f;
  for (int v = t; v < 32768; v += 256) s += ldin(masks, ((size_t)k << 15) + v, f32);
  __shared__ float red[256];
  red[t] = s; __syncthreads();
  for (int off = 128; off > 0; off >>= 1) { if (t < off) red[t] += red[t + off]; __syncthreads(); }
  if (t == 0) ws[MSUM_OFF + k] = red[0];
}

// ---------------- rf partials + channel Gram ----------------
__global__ __launch_bounds__(256) void k_rfgram(const void* __restrict__ Z,
                                                const void* __restrict__ masks,
                                                float* __restrict__ ws) {
  __shared__ float Zt[64][68];
  __shared__ float Mt[64][36];
  int b = blockIdx.y, t = threadIdx.x;
  bool f32 = ws[FLAG_OFF] > 0.5f;
  int ci = t & 15, gj = t >> 4;
  int c0 = ci << 2, c20 = gj << 2, k0 = gj << 1;
  float accG[16], accR[8];
#pragma unroll
  for (int i = 0; i < 16; i++) accG[i] = 0.f;
#pragma unroll
  for (int i = 0; i < 8; i++) accR[i] = 0.f;
  int vs = blockIdx.x << 9;
  for (int t8 = 0; t8 < 8; t8++) {
    int vb = vs + (t8 << 6);
    __syncthreads();
    if (f32) {
      const float* Zf = (const float*)Z;
      const float* Mf = (const float*)masks;
#pragma unroll
      for (int i = 0; i < 8; i++) {
        int idx = (i << 8) + t, c = idx >> 5, v2 = (idx & 31) << 1;
        float2 u = *(const float2*)(Zf + (((size_t)(b << 6) + c) << 15) + vb + v2);
        Zt[v2][c] = u.x; Zt[v2 + 1][c] = u.y;
      }
#pragma unroll
      for (int i = 0; i < 4; i++) {
        int idx = (i << 8) + t, k = idx >> 5, v2 = (idx & 31) << 1;
        float2 u = *(const float2*)(Mf + ((size_t)k << 15) + vb + v2);
        Mt[v2][k] = u.x; Mt[v2 + 1][k] = u.y;
      }
    } else {
      const u16* Zs = (const u16*)Z;
      const u16* Ms = (const u16*)masks;
#pragma unroll
      for (int i = 0; i < 8; i++) {
        int idx = (i << 8) + t, c = idx >> 5, v2 = (idx & 31) << 1;
        unsigned int u = *(const unsigned int*)(Zs + (((size_t)(b << 6) + c) << 15) + vb + v2);
        Zt[v2][c]     = bf2f((u16)(u & 0xffff));
        Zt[v2 + 1][c] = bf2f((u16)(u >> 16));
      }
#pragma unroll
      for (int i = 0; i < 4; i++) {
        int idx = (i << 8) + t, k = idx >> 5, v2 = (idx & 31) << 1;
        unsigned int u = *(const unsigned int*)(Ms + ((size_t)k << 15) + vb + v2);
        Mt[v2][k]     = bf2f((u16)(u & 0xffff));
        Mt[v2 + 1][k] = bf2f((u16)(u >> 16));
      }
    }
    __syncthreads();
    for (int vt = 0; vt < 64; vt++) {
      float4 z1 = *(const float4*)&Zt[vt][c0];
      float4 z2 = *(const float4*)&Zt[vt][c20];
      float2 m2 = *(const float2*)&Mt[vt][k0];
      float z1a[4] = {z1.x, z1.y, z1.z, z1.w};
      float z2a[4] = {z2.x, z2.y, z2.z, z2.w};
      float m2a[2] = {m2.x, m2.y};
#pragma unroll
      for (int i = 0; i < 4; i++) {
#pragma unroll
        for (int j = 0; j < 4; j++) accG[(i << 2) + j] += z1a[i] * z2a[j];
#pragma unroll
        for (int kk = 0; kk < 2; kk++) accR[(i << 1) + kk] += z1a[i] * m2a[kk];
      }
    }
  }
  float* Gd = ws + G_OFF + (b << 12);
  float* Rd = ws + RF_OFF + (b << 11);
#pragma unroll
  for (int i = 0; i < 4; i++) {
#pragma unroll
    for (int j = 0; j < 4; j++) atomicAdd(Gd + ((c0 + i) << 6) + c20 + j, accG[(i << 2) + j]);
#pragma unroll
    for (int kk = 0; kk < 2; kk++) atomicAdd(Rd + ((k0 + kk) << 6) + c0 + i, accR[(i << 1) + kk]);
  }
}

// ---------------- scale rf, emit fp32 rf ----------------
__global__ void k_scale_rf(float* __restrict__ ws, float* __restrict__ out) {
  int i = blockIdx.x * 256 + threadIdx.x;  // < 24576
  int k = (i >> 6) & 31;
  float v = ws[RF_OFF + i] / (ws[MSUM_OFF + k] + 1e-6f);
  ws[RF_OFF + i] = v;
  out[RF_OUT + i] = v;
}

// ---------------- region Gram: ipk[k][i][j] = <rf[i,k,:], rf[j,k,:]> ----------------
__global__ void k_ipk(float* __restrict__ ws) {
  __shared__ float rfk[12][65];   // +1 pad: avoid same-bank i-stride
  int k = blockIdx.x, t = threadIdx.x;
  for (int i = t; i < 768; i += 256) {
    int b = i >> 6, c = i & 63;
    rfk[b][c] = ws[RF_OFF + (((size_t)(b << 5) + k) << 6) + c];
  }
  __syncthreads();
  if (t < 144) {
    int i = t / 12, j = t - (t / 12) * 12;
    float s = 0.f;
#pragma unroll
    for (int c = 0; c < 64; c++) s += rfk[i][c] * rfk[j][c];
    ws[IPK_OFF + k * 144 + t] = s;
  }
}

// ---------------- MMD (128-way parallel) + reg + Wk weights ----------------
__global__ void k_mmdw(const int* __restrict__ labels, const void* __restrict__ ages,
                       const void* __restrict__ prior, float* __restrict__ ws) {
  __shared__ float IPL[32 * 145];   // stride 145: bank-spread across k
  __shared__ float dpart[128];
  __shared__ float Dm[32], nms[32], bases[32], pwl[32];
  __shared__ int labs[12];
  int t = threadIdx.x;
  bool f32 = ws[FLAG_OFF] > 0.5f;
  if (t < 12) labs[t] = labels[t];
  for (int i = t; i < 4608; i += 256) {
    int k = i / 144, r = i - k * 144;
    IPL[k * 145 + r] = ws[IPK_OFF + i];
  }
  __syncthreads();
  if (t < 128) {
    int k = t >> 2, s = t & 3;
    const float inv2s2[4] = {50.f, 2.f, 0.5f, 0.125f};   // 1/(2*sigma^2)
    float inv = inv2s2[s];
    const float* pk = IPL + k * 145;
    // class counts (labels wave-uniform)
    float c0 = 0.f, c1 = 0.f, c2 = 0.f;
#pragma unroll
    for (int i = 0; i < 12; i++) {
      int li = labs[i];
      c0 += (li == 0) ? 1.f : 0.f;
      c1 += (li == 1) ? 1.f : 0.f;
      c2 += (li == 2) ? 1.f : 0.f;
    }
    float s00=0,s01=0,s02=0,s10=0,s11=0,s12=0,s20=0,s21=0,s22=0;
    float dg0=0, dg1=0, dg2=0;
    for (int i = 0; i < 12; i++) {
      int li = labs[i];                    // wave-uniform
      float x2i = pk[i * 13];              // diagonal = |rf_i|^2
      float r0=0, r1=0, r2=0, dge=0;
      for (int j = 0; j < 12; j++) {
        float d2 = fmaxf(x2i + pk[j * 13] - 2.f * pk[i * 12 + j], 0.f);
        float e = expf(-d2 * inv);
        int lj = labs[j];                  // wave-uniform
        r0 += (lj == 0) ? e : 0.f;
        r1 += (lj == 1) ? e : 0.f;
        r2 += (lj == 2) ? e : 0.f;
        if (j == i) dge = e;
      }
      if (li == 0)      { s00 += r0; s01 += r1; s02 += r2; dg0 += dge; }
      else if (li == 1) { s10 += r0; s11 += r1; s12 += r2; dg1 += dge; }
      else              { s20 += r0; s21 += r1; s22 += r2; dg2 += dge; }
    }
    float ta = (s22 - dg2) / (c2 * (c2 - 1.f));
    float tb = (s00 - dg0) / (c0 * (c0 - 1.f));
    float tc = (s11 - dg1) / (c1 * (c1 - 1.f));
    float dsum = (ta + tb - 2.f * s20 / (c2 * c0))     // (AD,CN)
               + (tc + tb - 2.f * s10 / (c1 * c0))     // (MCI,CN)
               + (ta + tc - 2.f * s21 / (c2 * c1));    // (AD,MCI)
    dpart[t] = dsum;
  }
  __syncthreads();
  if (t < 32) {
    Dm[t] = (dpart[t * 4] + dpart[t * 4 + 1] + dpart[t * 4 + 2] + dpart[t * 4 + 3]) * 0.25f;
    pwl[t] = (float)ldin(prior, t, f32);
  }
  __syncthreads();
  if (t == 0) {
    float mx = 1e-6f;
    for (int k = 0; k < 32; k++) mx = fmaxf(mx, Dm[k]);
    float nmax = -1e30f, pmax = -1e30f;
    for (int k = 0; k < 32; k++) {
      nms[k] = fmaxf(Dm[k] / mx, 0.f);
      nmax = fmaxf(nmax, nms[k]);
      pmax = fmaxf(pmax, pwl[k]);
    }
    float nse = 0.f, pse = 0.f;
    for (int k = 0; k < 32; k++) { nse += expf(nms[k] - nmax); pse += expf(pwl[k] - pmax); }
    float lns = logf(nse), lps = logf(pse);
    float reg = 0.f;
    for (int k = 0; k < 32; k++) {
      float lqk = nms[k] - nmax - lns;
      float lpk = pwl[k] - pmax - lps;
      reg += 0.5f * (expf(lqk) * (lqk - lpk) + expf(lpk) * (lpk - lqk));
    }
    ws[REG_OFF] = reg / 32.f;
    for (int k = 0; k < 32; k++) bases[k] = 0.7f * pwl[k] + 0.3f * nms[k];
  }
  __syncthreads();
  if (t < 12) {
    float x = 0.1f * (ldin(ages, t, f32) - 50.f);
    float af = 1.f + fmaxf(x, 0.f) + log1pf(expf(-fabsf(x)));
    float w[32];
    float mx = -1e30f;
#pragma unroll
    for (int k = 0; k < 32; k++) {
      float v = fminf(fmaxf(bases[k] * af, 0.f), 2.f);
      w[k] = v; mx = fmaxf(mx, v);
    }
    float se = 0.f;
#pragma unroll
    for (int k = 0; k < 32; k++) se += expf(w[k] - mx);
#pragma unroll
    for (int k = 0; k < 32; k++) ws[WKW_OFF + (t << 5) + k] = expf(w[k] - mx) / se;
  }
}

// ---------------- channel modulation MLP per (b,k) -> modT bf16 ----------------
__global__ __launch_bounds__(64) void k_mod(const void* __restrict__ m_w1, const void* __restrict__ m_b1,
                                            const void* __restrict__ m_w2, const void* __restrict__ m_b2,
                                            float* __restrict__ ws) {
  __shared__ float W1[16][65];   // padded
  __shared__ float W2T[16][64];  // transposed: [rr][c]
  __shared__ float B1[16], B2[64], RL[64], H[16];
  int bk = blockIdx.x, t = threadIdx.x;
  int bb = bk >> 5, kk = bk & 31;
  bool f32 = ws[FLAG_OFF] > 0.5f;
  for (int i = t; i < 1024; i += 64) {
    W1[i >> 6][i & 63] = ldin(m_w1, i, f32);      // m_w1[rr][c]
    W2T[i & 15][i >> 4] = ldin(m_w2, i, f32);     // m_w2[c][rr] -> [rr][c]
  }
  if (t < 16) B1[t] = ldin(m_b1, t, f32);
  B2[t] = ldin(m_b2, t, f32);
  RL[t] = ws[RF_OFF + (bk << 6) + t];
  __syncthreads();
  if (t < 16) {
    float s = B1[t];
#pragma unroll
    for (int c = 0; c < 64; c++) s += RL[c] * W1[t][c];
    H[t] = fmaxf(s, 0.f);
  }
  __syncthreads();
  {
    int c = t;
    float s = B2[c];
#pragma unroll
    for (int rr = 0; rr < 16; rr++) s += H[rr] * W2T[rr][c];
    float mv = fmaxf(s, 0.f) + log1pf(expf(-fabsf(s)));
    ((u16*)(ws + MODTB_OFF))[((size_t)bb * 64 + c) * 32 + kk] = f2bf(mv);
  }
}

// ---------------- M1T^T = (up_w @ struct_w)^T, bf16 hi/lo ----------------
__global__ void k_m1t(const void* __restrict__ struct_w, const void* __restrict__ up_w,
                      float* __restrict__ ws) {
  __shared__ float UPT[32][64];  // transposed: [j][co]
  __shared__ float ST[32][64];   // [j][cin]
  int t = threadIdx.x, blk = blockIdx.x;
  bool f32 = ws[FLAG_OFF] > 0.5f;
  for (int i = t; i < 2048; i += 256) {
    UPT[i & 31][i >> 5] = ldin(up_w, i, f32);     // up_w[co][j] -> [j][co]
    ST[i >> 6][i & 63] = ldin(struct_w, i, f32);  // struct_w[j][cin]
  }
  __syncthreads();
  int idx = (blk << 8) + t;   // 0..4095
  int cin = idx >> 6, co = idx & 63;
  float s = 0.f;
#pragma unroll
  for (int j = 0; j < 32; j++) s += UPT[j][co] * ST[j][cin];
  u16 hi = f2bf(s);
  ((u16*)(ws + M1TTH_OFF))[co * 64 + cin] = hi;
  ((u16*)(ws + M1TTL_OFF))[co * 64 + cin] = f2bf(s - bf2f(hi));
}

// ---------------- ortho from Gram ----------------
__global__ void k_ortho(const void* __restrict__ sw, const void* __restrict__ nw,
                        float* __restrict__ ws) {
  int b = blockIdx.x >> 5, o = blockIdx.x & 31, c = threadIdx.x;
  bool f32 = ws[FLAG_OFF] > 0.5f;
  const float* Gb = ws + G_OFF + (b << 12);
  float ts = 0.f, tn = 0.f;
  for (int c2 = 0; c2 < 64; c2++) {
    float g = Gb[(c << 6) + c2];
    ts += g * ldin(sw, (o << 6) + c2, f32);
    tn += g * ldin(nw, (o << 6) + c2, f32);
  }
  float swc = ldin(sw, (o << 6) + c, f32);
  float nwc = ldin(nw, (o << 6) + c, f32);
  float ds = swc * tn, ss = swc * ts, nn = nwc * tn;
  for (int off = 32; off > 0; off >>= 1) {
    ds += __shfl_down(ds, off);
    ss += __shfl_down(ss, off);
    nn += __shfl_down(nn, off);
  }
  if (c == 0) {
    ss = fmaxf(ss, 0.f); nn = fmaxf(nn, 0.f);
    float cosv = ds / (fmaxf(sqrtf(ss), 1e-8f) * fmaxf(sqrtf(nn), 1e-8f));
    atomicAdd(ws + ORTHO_OFF, fabsf(cosv) * (1.f / 384.f));
  }
}

// ---------------- folded conv weights -> bf16 [b][o][d][k] ----------------
__global__ void k_wk(const void* __restrict__ rw, float* __restrict__ ws) {
  int bk = blockIdx.x;  // b*32+k
  int b = bk >> 5, k = bk & 31;
  int t = threadIdx.x;
  bool f32 = ws[FLAG_OFF] > 0.5f;
  __shared__ float rl[64];
  if (t < 64) rl[t] = ws[RF_OFF + (bk << 6) + t];
  __syncthreads();
  u16* dst = (u16*)(ws + WKCB_OFF);
  for (int idx = t; idx < 1728; idx += 256) {
    int o = idx / 27, d = idx - o * 27;
    float s = 0.f;
    for (int c = 0; c < 64; c++) s += rl[c] * ldin(rw, (size_t)o * 1728 + c * 27 + d, f32);
    dst[(((size_t)b * 64 + o) * 27 + d) * 32 + k] = f2bf(s);   // kd = d*32+k
  }
}

// ---------------- spatial output (fp32) ----------------
__global__ void k_spatial(const void* __restrict__ masks, const float* __restrict__ ws,
                          float* __restrict__ out) {
  int b = blockIdx.y, t = threadIdx.x;
  bool f32 = ws[FLAG_OFF] > 0.5f;
  __shared__ float wl[32];
  if (t < 32) wl[t] = ws[WKW_OFF + (b << 5) + t];
  __syncthreads();
  int v0 = (blockIdx.x << 11) + (t << 3);
  float s[8] = {0, 0, 0, 0, 0, 0, 0, 0};
  for (int k = 0; k < 32; k++) {
    float wkv = wl[k];
    float mv[8];
    if (f32) {
      const float* Mf = (const float*)masks + ((size_t)k << 15) + v0;
      float4 a = *(const float4*)Mf, bb = *(const float4*)(Mf + 4);
      mv[0]=a.x; mv[1]=a.y; mv[2]=a.z; mv[3]=a.w; mv[4]=bb.x; mv[5]=bb.y; mv[6]=bb.z; mv[7]=bb.w;
    } else {
      uint4 u = *(const uint4*)((const u16*)masks + ((size_t)k << 15) + v0);
      mv[0]=bf2f((u16)(u.x & 0xffff)); mv[1]=bf2f((u16)(u.x >> 16));
      mv[2]=bf2f((u16)(u.y & 0xffff)); mv[3]=bf2f((u16)(u.y >> 16));
      mv[4]=bf2f((u16)(u.z & 0xffff)); mv[5]=bf2f((u16)(u.z >> 16));
      mv[6]=bf2f((u16)(u.w & 0xffff)); mv[7]=bf2f((u16)(u.w >> 16));
    }
#pragma unroll
    for (int j = 0; j < 8; j++) s[j] += wkv * mv[j];
  }
#pragma unroll
  for (int j = 0; j < 8; j++) out[SPAT_OUT + (b << 15) + v0 + j] = s[j];
}

// ---------------- fused final: MFMA GEMM, global-bitmask halo, w-major tile ----------------
// Tile = 2d x 4h x 32w (full w rows): 16 consecutive lanes = 64B contiguous for
// Z loads AND C stores (fixes r6's 2x write amplification from 32B chunks).
// Halo from precomputed MB[v] bitmask (k_mb): ~4 coalesced u32 loads/thread
// replaces r6's 75 scattered mask reads/thread (-118 MB HBM fetch).
// Halo LDS: MHB[4 d][6 h][40 w-stride] u32 = 3.75 KB.
#define MHW 40
__global__ __launch_bounds__(256, 4) void k_final(const void* __restrict__ Z,
                                                  const void* __restrict__ masks,
                                                  const float* __restrict__ ws,
                                                  float* __restrict__ out) {
  __shared__ unsigned int MHB[4 * 6 * MHW];   // 960 u32
  __shared__ float wl[32];
  __shared__ float spl[256];
  (void)masks;

  int b = blockIdx.y, tile = blockIdx.x, t = threadIdx.x;
  int lane = t & 63, w = t >> 6;
  int lo16 = lane & 15, g = lane >> 4, g8 = g << 3;
  int d0 = (tile >> 3) << 1, h0 = (tile & 7) << 2;   // 16 x 8 = 128 tiles
  const unsigned int* MB = (const unsigned int*)(ws + MB_OFF);
  bool f32 = ws[FLAG_OFF] > 0.5f;

  // ---- phase 0: halo bitmask from MB (coalesced u32 rows) ----
  for (int i = t; i < 4 * 6 * MHW; i += 256) {
    int hd = i / (6 * MHW), r = i - hd * (6 * MHW), hh = r / MHW, hw = r - hh * MHW;
    int gd = d0 - 1 + hd, gh = h0 - 1 + hh, gw = hw - 1;
    unsigned int word = 0;
    if ((unsigned)gd < 32u && (unsigned)gh < 32u && (unsigned)gw < 32u)
      word = MB[(gd << 10) + (gh << 5) + gw];
    MHB[i] = word;
  }
  if (t < 32) wl[t] = ws[WKW_OFF + (b << 5) + t];
  __syncthreads();

  // per-thread pos: spl[pos = t]; pos = dz*128 + hy*32 + wx
  {
    int dz = t >> 7, hy = (t >> 5) & 3, wx = t & 31;
    unsigned int m = MHB[((dz + 1) * 6 + hy + 1) * MHW + wx + 1];
    float sp = 0.f;
#pragma unroll
    for (int k = 0; k < 32; k++) sp += ((m >> k) & 1u) ? wl[k] : 0.f;
    spl[t] = sp;
  }

  // per-lane tile columns: pos = w*64 + pt*16 + lo16
  int hb4[4], v4[4];
#pragma unroll
  for (int pt = 0; pt < 4; pt++) {
    int pos = (w << 6) + (pt << 4) + lo16;
    int dz = pos >> 7, hy = (pos >> 5) & 3, wx = pos & 31;
    hb4[pt] = (dz * 6 + hy) * MHW + wx;   // halo base (da=db=dc=0)
    v4[pt] = ((d0 + dz) << 10) + ((h0 + hy) << 5) + wx;
  }

  fv4 acc[4][4];
#pragma unroll
  for (int ot = 0; ot < 4; ot++)
#pragma unroll
    for (int pt = 0; pt < 4; pt++) { acc[ot][pt][0]=0.f; acc[ot][pt][1]=0.f; acc[ot][pt][2]=0.f; acc[ot][pt][3]=0.f; }

  // ---- phase 1: conv GEMM, 27 K-steps (one spatial offset each) ----
  const u16* Wb = (const u16*)(ws + WKCB_OFF) + (size_t)b * 55296;
#pragma unroll 3
  for (int d = 0; d < 27; d++) {
    int da = d / 9, r9 = d - da * 9, db = r9 / 3, dc = r9 - db * 3;
    int off = (da * 6 + db) * MHW + dc;             // wave-uniform
    bh8 a[4];
#pragma unroll
    for (int ot = 0; ot < 4; ot++)
      a[ot] = *(const bh8*)(Wb + ((ot << 4) + lo16) * 864 + (d << 5) + g8);
#pragma unroll
    for (int pt = 0; pt < 4; pt++) {
      bh8 bv = bits2bf8(MHB[hb4[pt] + off] >> g8);
#pragma unroll
      for (int ot = 0; ot < 4; ot++)
        acc[ot][pt] = __builtin_amdgcn_mfma_f32_16x16x32_bf16(a[ot], bv, acc[ot][pt], 0, 0, 0);
    }
  }

  // ---- phase 2: mod GEMM (K=32) + fold; center off = (1*6+1)*MHW+1 ----
  {
    const u16* modtb = (const u16*)(ws + MODTB_OFF);
    bh8 am[4];
#pragma unroll
    for (int ot = 0; ot < 4; ot++)
      am[ot] = *(const bh8*)(modtb + ((size_t)b * 64 + (ot << 4) + lo16) * 32 + g8);
    fv4 zero4; zero4[0]=0.f; zero4[1]=0.f; zero4[2]=0.f; zero4[3]=0.f;
#pragma unroll
    for (int pt = 0; pt < 4; pt++) {
      bh8 bc = bits2bf8(MHB[hb4[pt] + 7 * MHW + 1] >> g8);
      float spf = 0.1f * spl[(w << 6) + (pt << 4) + lo16];
#pragma unroll
      for (int ot = 0; ot < 4; ot++) {
        fv4 mm = __builtin_amdgcn_mfma_f32_16x16x32_bf16(am[ot], bc, zero4, 0, 0, 0);
        acc[ot][pt] = acc[ot][pt] * mm * spf;
      }
    }
  }

  // ---- phase 3: Z_clean GEMM, B-fragments direct from global (64B coalesced) ----
  {
    const u16* m1tth = (const u16*)(ws + M1TTH_OFF);
    const u16* m1ttl = (const u16*)(ws + M1TTL_OFF);
#pragma unroll 1
    for (int st = 0; st < 2; st++) {
      int cb = st << 5;
#pragma unroll
      for (int pt = 0; pt < 4; pt++) {
        bh8 bh, bl;
#pragma unroll
        for (int j = 0; j < 8; j++) {
          float zv = ldin(Z, (((size_t)(b << 6) + cb + g8 + j) << 15) + v4[pt], f32);
          u16 h = f2bf(zv);
          bh[j] = (short)h;
          bl[j] = (short)f2bf(zv - bf2f(h));
        }
#pragma unroll
        for (int ot = 0; ot < 4; ot++) {
          bh8 ah = *(const bh8*)(m1tth + ((ot << 4) + lo16) * 64 + cb + g8);
          bh8 al = *(const bh8*)(m1ttl + ((ot << 4) + lo16) * 64 + cb + g8);
          acc[ot][pt] = __builtin_amdgcn_mfma_f32_16x16x32_bf16(ah, bh, acc[ot][pt], 0, 0, 0);
          acc[ot][pt] = __builtin_amdgcn_mfma_f32_16x16x32_bf16(ah, bl, acc[ot][pt], 0, 0, 0);
          acc[ot][pt] = __builtin_amdgcn_mfma_f32_16x16x32_bf16(al, bh, acc[ot][pt], 0, 0, 0);
        }
      }
    }
  }

  // ---- phase 4: store (D layout: row o = ot*16+g*4+r, col pos = pt*16+lo16) ----
#pragma unroll
  for (int ot = 0; ot < 4; ot++)
#pragma unroll
    for (int pt = 0; pt < 4; pt++)
#pragma unroll
      for (int r = 0; r < 4; r++) {
        int o = (ot << 4) + (g << 2) + r;
        out[(size_t)ZOUT_OUT + (((size_t)(b << 6) + o) << 15) + v4[pt]] = acc[ot][pt][r];
      }
  if ((t | tile | b) == 0) out[SCAL_OUT] = ws[REG_OFF] + ws[ORTHO_OFF];
}

extern "C" void kernel_launch(void* const* d_in, const int* in_sizes, int n_in,
                              void* d_out, int out_size, void* d_ws, size_t ws_size,
                              hipStream_t stream) {
  (void)in_sizes; (void)n_in; (void)out_size; (void)ws_size;
  const void* Z        = d_in[0];
  const void* masks    = d_in[1];
  const int*  labels   = (const int*)d_in[2];
  const void* ages     = d_in[3];
  const void* prior    = d_in[4];
  const void* struct_w = d_in[5];
  const void* noise_w  = d_in[6];
  const void* up_w     = d_in[7];
  const void* region_w = d_in[8];
  const void* m_w1     = d_in[9];
  const void* m_b1     = d_in[10];
  const void* m_w2     = d_in[11];
  const void* m_b2     = d_in[12];
  float* ws = (float*)d_ws;
  float* out = (float*)d_out;

  hipMemsetAsync(d_ws, 0, (size_t)ZERO_FLOATS * 4, stream);
  k_probe<<<1, 256, 0, stream>>>(Z, ws);
  k_mb<<<128, 256, 0, stream>>>(masks, ws);
  k_msum<<<32, 256, 0, stream>>>(masks, ws);
  k_rfgram<<<dim3(64, 12), 256, 0, stream>>>(Z, masks, ws);
  k_scale_rf<<<96, 256, 0, stream>>>(ws, out);
  k_m1t<<<16, 256, 0, stream>>>(struct_w, up_w, ws);
  k_ipk<<<32, 256, 0, stream>>>(ws);
  k_mmdw<<<1, 256, 0, stream>>>(labels, ages, prior, ws);
  k_mod<<<384, 64, 0, stream>>>(m_w1, m_b1, m_w2, m_b2, ws);
  k_ortho<<<384, 64, 0, stream>>>(struct_w, noise_w, ws);
  k_wk<<<384, 256, 0, stream>>>(region_w, ws);
  k_spatial<<<dim3(16, 12), 256, 0, stream>>>(masks, ws, out);
  k_final<<<dim3(128, 12), 256, 0, stream>>>(Z, masks, ws, out);
}